// Round 1
// baseline (505.593 us; speedup 1.0000x reference)
//
#include <hip/hip_runtime.h>

// VanillaRNN: B=4096, T=1024, I=3, H=32, O=2
// out[b,t,j] = h_t[j];  h_t = tanh(x_t @ W_ih^T + b_ih + b_hh + h_{t-1} @ W_hh^T)
// h_n[b,o] = h_T @ W_fc^T + b_fc
//
// Layout: lane = (batch, j). 32 lanes per batch element, 2 batch/wave,
// 8 batch/block (256 threads). h in LDS, W_hh row-j in 32 VGPRs/lane.
// All h exchange is wave-internal -> no __syncthreads anywhere.

#define RNN_B 4096
#define RNN_T 1024
#define RNN_H 32
#define GROUPS 8              // batch elements per block
#define BLOCK (GROUPS * 32)   // 256 threads

__global__ __launch_bounds__(BLOCK) void vanilla_rnn_kernel(
    const float* __restrict__ x,     // [B,T,3]
    const float* __restrict__ W_ih,  // [32,3]
    const float* __restrict__ b_ih,  // [32]
    const float* __restrict__ W_hh,  // [32,32]
    const float* __restrict__ b_hh,  // [32]
    const float* __restrict__ W_fc,  // [2,32]
    const float* __restrict__ b_fc,  // [2]
    float* __restrict__ out,         // [B,T,32]
    float* __restrict__ hn_out)      // [B,2]
{
    const int tid = threadIdx.x;
    const int g   = tid >> 5;        // group (batch) within block
    const int j   = tid & 31;        // output index within H
    const int b   = blockIdx.x * GROUPS + g;

    __shared__ float hs[GROUPS][32]; // current hidden state per group

    // Per-lane: row j of W_hh (h @ W_hh^T  =>  out[j] = sum_k h[k]*W_hh[j][k])
    float W[32];
#pragma unroll
    for (int k = 0; k < 32; ++k) W[k] = W_hh[j * 32 + k];

    const float wi0 = W_ih[j * 3 + 0];
    const float wi1 = W_ih[j * 3 + 1];
    const float wi2 = W_ih[j * 3 + 2];
    const float bsum = b_ih[j] + b_hh[j];

    hs[g][j] = 0.0f;                 // h0 = 0 (wave-internal, no barrier needed)

    const float* xb = x + (size_t)b * RNN_T * 3;
    float*       ob = out + (size_t)b * RNN_T * RNN_H;

    // software prefetch of x (distance 1)
    float x0 = xb[0], x1 = xb[1], x2 = xb[2];

    for (int t = 0; t < RNN_T; ++t) {
        const int tn = (t + 1 < RNN_T) ? (t + 1) : (RNN_T - 1);
        const float nx0 = xb[tn * 3 + 0];
        const float nx1 = xb[tn * 3 + 1];
        const float nx2 = xb[tn * 3 + 2];

        float acc = bsum + wi0 * x0 + wi1 * x1 + wi2 * x2;

        // h @ W_hh^T : broadcast-read h as float4 from LDS
        const float4* h4 = (const float4*)(&hs[g][0]);
#pragma unroll
        for (int k4 = 0; k4 < 8; ++k4) {
            const float4 hv = h4[k4];
            acc += W[k4 * 4 + 0] * hv.x;
            acc += W[k4 * 4 + 1] * hv.y;
            acc += W[k4 * 4 + 2] * hv.z;
            acc += W[k4 * 4 + 3] * hv.w;
        }

        // tanh(acc) = 1 - 2/(exp(2*acc)+1); correct at +-inf
        const float e  = __expf(2.0f * acc);
        const float th = 1.0f - 2.0f / (e + 1.0f);

        ob[t * RNN_H + j] = th;
        hs[g][j] = th;               // visible to same-wave reads next iter

        x0 = nx0; x1 = nx1; x2 = nx2;
    }

    // h_n = h_T @ W_fc^T + b_fc   (only 2 outputs per batch)
    if (j < 2) {
        float acc = b_fc[j];
#pragma unroll
        for (int k = 0; k < 32; ++k) acc += W_fc[j * 32 + k] * hs[g][k];
        hn_out[(size_t)b * 2 + j] = acc;
    }
}

extern "C" void kernel_launch(void* const* d_in, const int* in_sizes, int n_in,
                              void* d_out, int out_size, void* d_ws, size_t ws_size,
                              hipStream_t stream) {
    const float* x    = (const float*)d_in[0];
    const float* W_ih = (const float*)d_in[1];
    const float* b_ih = (const float*)d_in[2];
    const float* W_hh = (const float*)d_in[3];
    const float* b_hh = (const float*)d_in[4];
    const float* W_fc = (const float*)d_in[5];
    const float* b_fc = (const float*)d_in[6];

    float* out    = (float*)d_out;                                   // [B,T,H]
    float* hn_out = out + (size_t)RNN_B * RNN_T * RNN_H;             // [B,2]

    const int grid = RNN_B / GROUPS;  // 512 blocks
    vanilla_rnn_kernel<<<grid, BLOCK, 0, stream>>>(
        x, W_ih, b_ih, W_hh, b_hh, W_fc, b_fc, out, hn_out);
}

// Round 2
// 232.860 us; speedup vs baseline: 2.1712x; 2.1712x over previous
//
#include <hip/hip_runtime.h>

// VanillaRNN: B=4096, T=1024, I=3, H=32, O=2
// out[b,t,j] = h_t[j];  h_t = tanh(x_t @ W_ih^T + b_ih + b_hh + h_{t-1} @ W_hh^T)
// h_n[b,o] = h_T @ W_fc^T + b_fc
//
// Layout: lane = (batch, j). 32 lanes per batch element, 2 batch/wave,
// 8 batch/block (256 threads). h in LDS, W_hh row-j in 32 VGPRs/lane.
// All h exchange is wave-internal -> no __syncthreads anywhere.
//
// R2 changes vs R1 (theory: ~900 cyc/step stall was x-load latency at
// prefetch distance 1 + 32-deep serial FMA chain + IEEE divide in tanh):
//  - T-loop unrolled x4, x prefetched one full block (4 steps) ahead
//  - 4 independent accumulators (chain 128 -> ~40 cyc)
//  - all 8 ds_read_b128 of h issued up front (latency overlap)
//  - tanh uses v_rcp_f32 (approx rcp) instead of IEEE divide expansion
//  - nontemporal stores for out (write-once, never re-read)

#define RNN_B 4096
#define RNN_T 1024
#define RNN_H 32
#define GROUPS 8              // batch elements per block
#define BLOCK (GROUPS * 32)   // 256 threads
#define DEPTH 4               // T-unroll / x prefetch distance

__global__ __launch_bounds__(BLOCK) void vanilla_rnn_kernel(
    const float* __restrict__ x,     // [B,T,3]
    const float* __restrict__ W_ih,  // [32,3]
    const float* __restrict__ b_ih,  // [32]
    const float* __restrict__ W_hh,  // [32,32]
    const float* __restrict__ b_hh,  // [32]
    const float* __restrict__ W_fc,  // [2,32]
    const float* __restrict__ b_fc,  // [2]
    float* __restrict__ out,         // [B,T,32]
    float* __restrict__ hn_out)      // [B,2]
{
    const int tid = threadIdx.x;
    const int g   = tid >> 5;        // group (batch) within block
    const int j   = tid & 31;        // output index within H
    const int b   = blockIdx.x * GROUPS + g;

    __shared__ float hs[GROUPS][32]; // current hidden state per group

    // Per-lane: row j of W_hh (h @ W_hh^T  =>  out[j] = sum_k h[k]*W_hh[j][k])
    float W[32];
#pragma unroll
    for (int k = 0; k < 32; ++k) W[k] = W_hh[j * 32 + k];

    const float wi0 = W_ih[j * 3 + 0];
    const float wi1 = W_ih[j * 3 + 1];
    const float wi2 = W_ih[j * 3 + 2];
    const float bsum = b_ih[j] + b_hh[j];

    hs[g][j] = 0.0f;                 // h0 = 0 (wave-internal, no barrier needed)

    const float* xb = x + (size_t)b * RNN_T * 3;
    float*       ob = out + (size_t)b * RNN_T * RNN_H;

    // x prefetch buffer: one full unroll block ahead
    float xs[DEPTH][3];
#pragma unroll
    for (int d = 0; d < DEPTH; ++d) {
#pragma unroll
        for (int c = 0; c < 3; ++c) xs[d][c] = xb[d * 3 + c];
    }

    for (int tb = 0; tb < RNN_T; tb += DEPTH) {
        // issue next block's x loads now; consumed only after the 4-step body
        const int tnb = (tb + DEPTH < RNN_T) ? (tb + DEPTH) : tb;
        float nxs[DEPTH][3];
#pragma unroll
        for (int d = 0; d < DEPTH; ++d) {
#pragma unroll
            for (int c = 0; c < 3; ++c) nxs[d][c] = xb[(tnb + d) * 3 + c];
        }

#pragma unroll
        for (int d = 0; d < DEPTH; ++d) {
            // read full h vector first: 8 independent ds_read_b128, latencies overlap
            const float4* h4 = (const float4*)(&hs[g][0]);
            float4 hv[8];
#pragma unroll
            for (int q = 0; q < 8; ++q) hv[q] = h4[q];

            // 4 independent accumulator chains (8 FMAs each)
            float a0 = fmaf(wi0, xs[d][0], bsum);
            float a1 = wi1 * xs[d][1];
            float a2 = wi2 * xs[d][2];
            float a3 = 0.0f;
#pragma unroll
            for (int q = 0; q < 8; ++q) {
                a0 = fmaf(W[4 * q + 0], hv[q].x, a0);
                a1 = fmaf(W[4 * q + 1], hv[q].y, a1);
                a2 = fmaf(W[4 * q + 2], hv[q].z, a2);
                a3 = fmaf(W[4 * q + 3], hv[q].w, a3);
            }
            const float acc = (a0 + a1) + (a2 + a3);

            // tanh(acc) = 1 - 2/(exp(2*acc)+1); rcp approx (~1 ulp), inf-safe
            const float e  = __expf(2.0f * acc);
            const float r  = __builtin_amdgcn_rcpf(e + 1.0f);
            const float th = fmaf(-2.0f, r, 1.0f);

            __builtin_nontemporal_store(th, &ob[(tb + d) * RNN_H + j]);
            hs[g][j] = th;           // same-wave LDS ordering -> visible next d
        }

#pragma unroll
        for (int d = 0; d < DEPTH; ++d) {
#pragma unroll
            for (int c = 0; c < 3; ++c) xs[d][c] = nxs[d][c];
        }
    }

    // h_n = h_T @ W_fc^T + b_fc   (only 2 outputs per batch)
    if (j < 2) {
        float acc = b_fc[j];
#pragma unroll
        for (int k = 0; k < 32; ++k) acc = fmaf(W_fc[j * 32 + k], hs[g][k], acc);
        hn_out[(size_t)b * 2 + j] = acc;
    }
}

extern "C" void kernel_launch(void* const* d_in, const int* in_sizes, int n_in,
                              void* d_out, int out_size, void* d_ws, size_t ws_size,
                              hipStream_t stream) {
    const float* x    = (const float*)d_in[0];
    const float* W_ih = (const float*)d_in[1];
    const float* b_ih = (const float*)d_in[2];
    const float* W_hh = (const float*)d_in[3];
    const float* b_hh = (const float*)d_in[4];
    const float* W_fc = (const float*)d_in[5];
    const float* b_fc = (const float*)d_in[6];

    float* out    = (float*)d_out;                                   // [B,T,H]
    float* hn_out = out + (size_t)RNN_B * RNN_T * RNN_H;             // [B,2]

    const int grid = RNN_B / GROUPS;  // 512 blocks
    vanilla_rnn_kernel<<<grid, BLOCK, 0, stream>>>(
        x, W_ih, b_ih, W_hh, b_hh, W_fc, b_fc, out, hn_out);
}